// Round 2
// baseline (73.462 us; speedup 1.0000x reference)
//
#include <hip/hip_runtime.h>
#include <math.h>

// cost = -(1/N^2) sum_ij sigmoid(p_i p_j) relu(t_i - t_j)
//      = -(1/(2N^2)) sum_ij sigmoid(p_i p_j) |t_i - t_j|
// Separable O(N*PB): sigmoid(p_i p_j) ~= sum_b w_b(p_j) sigmoid(p_i q_b)
//   => S = sum_i sum_b sigmoid(p_i q_b) * M_b(t_i),
//      M_b(t) = sum_j w_b(p_j)|t - t_j|  (exact at TB+1 t-nodes via prefix
//      sums over t-binned (w, w*t) histograms; lerped between nodes).
//
// R2: kill the redundant phase-A scan (R0/R1 evidence: per-block scan of
// all N is latency-bound, ~25us wall, invariant to blocks/CU).
//  - node1 bin_slices: 16 blocks, each zeroes a PRIVATE global histogram
//    slice (zero -> syncthreads -> bin, no cross-block ordering), bins
//    only its N/16 elements with global_atomic_add_f32. 256x less binning
//    work, latency hidden by 4096 independent threads. p-clamp makes all
//    columns in-range: no window check.
//  - node2 auc_main: 256 blocks merge the 16 slices for their 6 columns
//    (48 independent L2 loads/thread, fixed order = deterministic), then
//    phase B prefix-scan + phase C as R1. LDS stride 7 (gcd(7,32)=1).
//  - node3 reduce: deterministic fixed-order sum (unchanged).

#define TB 64                  // t-bins (TB+1 nodes); one wave64 scans it
#define PB 192                 // p-grid points over [PLO,PHI]
#define NS 16                  // binning slices (blocks in node1)
#define SLICE (2 * TB * PB)    // floats per slice: W[64][192] + P[64][192]
#define NBC 32                 // b-chunks
#define NBL 6                  // b per chunk = PB/NBC
#define NIC 8                  // i-chunks
#define NBLK (NBC * NIC)       // 256 blocks
#define NTHR 256
#define PLO (-5.0f)
#define PHI (5.0f)

__global__ __launch_bounds__(NTHR) void bin_slices(
    const float* __restrict__ t, const float* __restrict__ p,
    float* __restrict__ hist, int N)
{
    const int s   = blockIdx.x;
    const int tid = threadIdx.x;
    float* base = hist + s * SLICE;

    // zero OWN slice (private -> only block-local ordering needed)
    const float4 z = {0.0f, 0.0f, 0.0f, 0.0f};
    for (int i = tid; i < SLICE / 4; i += NTHR)
        ((float4*)base)[i] = z;
    __syncthreads();

    // bin own N/NS elements; all columns in-range by construction
    const float pscale = (float)(PB - 1) / (PHI - PLO);
    const int itersA = N / (NS * NTHR * 4);        // 1 for N=16384
    for (int it = 0; it < itersA; ++it) {
        const int j4 = s * (N / NS) + (it * NTHR + tid) * 4;
        const float4 tv = *(const float4*)(t + j4);
        const float4 pv = *(const float4*)(p + j4);
        const float te[4] = {tv.x, tv.y, tv.z, tv.w};
        const float pe[4] = {pv.x, pv.y, pv.z, pv.w};
#pragma unroll
        for (int e = 0; e < 4; ++e) {
            float x = (pe[e] - PLO) * pscale;
            x = fminf(fmaxf(x, 0.0f), (float)(PB - 1) - 1e-4f);
            const int b0 = (int)x;                 // <= PB-2
            const float f = x - (float)b0;
            const int tau = min(max((int)(te[e] * (float)TB), 0), TB - 1);
            float* w = base + tau * PB + b0;
            atomicAdd(w,     1.0f - f);
            atomicAdd(w + 1, f);
            float* q = w + TB * PB;
            atomicAdd(q,     (1.0f - f) * te[e]);
            atomicAdd(q + 1, f * te[e]);
        }
    }
}

__global__ __launch_bounds__(NTHR, 2) void auc_main(
    const float* __restrict__ t, const float* __restrict__ p,
    const float* __restrict__ hist, float* __restrict__ slots, int N)
{
    __shared__ float sW[TB][NBL + 1];      // stride 7: gcd(7,32)=1
    __shared__ float sP[TB][NBL + 1];
    __shared__ float sM[NBL][TB + 1];      // node tables
    __shared__ float s_red[4];

    const int bid = blockIdx.x;
    const int bc  = bid >> 3;              // / NIC
    const int ic  = bid & 7;               // % NIC
    const int B0  = bc * NBL;
    const int tid = threadIdx.x;

    // ---- merge: sum NS slices for this block's 6 columns (fixed order) ----
    for (int tgt = tid; tgt < 2 * TB * NBL; tgt += NTHR) {   // 768 targets
        int r = tgt, isP = 0;
        if (r >= TB * NBL) { isP = 1; r -= TB * NBL; }
        const int tau = r / NBL;
        const int cc  = r - tau * NBL;
        const float* g = hist + isP * (TB * PB) + tau * PB + B0 + cc;
        float a = 0.0f;
#pragma unroll
        for (int s2 = 0; s2 < NS; ++s2)
            a += g[s2 * SLICE];
        if (isP) sP[tau][cc] = a;
        else     sW[tau][cc] = a;
    }
    __syncthreads();

    // ---- phase B: node tables via one-wave prefix scan ----
    // M_b(g) = g*(2A - Wtot) + (Ptot - 2B), A/B = exclusive prefixes below g
    {
        const int wv = tid >> 6, lane = tid & 63;
        for (int cc = wv; cc < NBL; cc += 4) {   // waves cover cols 0..5
            const float w = sW[lane][cc];
            const float q = sP[lane][cc];
            float wi = w, qi = q;          // inclusive scans
#pragma unroll
            for (int off = 1; off < 64; off <<= 1) {
                const float wn = __shfl_up(wi, off, 64);
                const float qn = __shfl_up(qi, off, 64);
                if (lane >= off) { wi += wn; qi += qn; }
            }
            const float Wtot = __shfl(wi, 63, 64);
            const float Ptot = __shfl(qi, 63, 64);
            const float A = wi - w;        // exclusive
            const float B = qi - q;
            const float g = (float)lane * (1.0f / (float)TB);
            sM[cc][lane] = g * (2.0f * A - Wtot) + (Ptot - 2.0f * B);
            if (lane == 63) sM[cc][TB] = Wtot - Ptot;   // node g = 1
        }
    }
    __syncthreads();

    // ---- phase C: partial S over (i-chunk) x (6 owned b's) ----
    const float h = (PHI - PLO) / (float)(PB - 1);
    const float q0 = PLO + (float)B0 * h;
    const int i0 = ic * (N / NIC);
    float acc = 0.0f;
    const int itersC = (N / NIC) / (NTHR * 4);   // 2 for N=16384
    for (int it = 0; it < itersC; ++it) {
        const int i4 = i0 + (it * NTHR + tid) * 4;
        const float4 tv = *(const float4*)(t + i4);
        const float4 pv = *(const float4*)(p + i4);
        const float te[4] = {tv.x, tv.y, tv.z, tv.w};
        const float pe[4] = {pv.x, pv.y, pv.z, pv.w};
#pragma unroll
        for (int e = 0; e < 4; ++e) {
            const float c = pe[e] * -1.44269504088896340736f;  // -log2(e)*p_i
            float x = te[e] * (float)TB;
            const int k = min((int)x, TB - 1);
            const float f = x - (float)k;
#pragma unroll
            for (int cc = 0; cc < NBL; ++cc) {
                const float m0 = sM[cc][k];
                const float m1 = sM[cc][k + 1];
                const float m  = fmaf(f, m1 - m0, m0);          // M_b(t_i)
                const float qb = q0 + (float)cc * h;
                const float ex = __builtin_amdgcn_exp2f(c * qb);
                const float sg = __builtin_amdgcn_rcpf(1.0f + ex);
                acc = fmaf(sg, m, acc);
            }
        }
    }

    // ---- block reduce -> plain partial store (kernel boundary syncs) ----
#pragma unroll
    for (int off = 32; off > 0; off >>= 1)
        acc += __shfl_down(acc, off, 64);
    if ((tid & 63) == 0) s_red[tid >> 6] = acc;
    __syncthreads();
    if (tid == 0)
        slots[bid] = s_red[0] + s_red[1] + s_red[2] + s_red[3];
}

// One block: deterministic fixed-order sum of the 256 partials.
__global__ __launch_bounds__(NTHR) void auc_reduce(
    const float* __restrict__ slots, float* __restrict__ out, float scale)
{
    __shared__ float s_red[4];
    const int tid = threadIdx.x;
    float v = slots[tid];                  // NBLK == NTHR == 256
#pragma unroll
    for (int off = 32; off > 0; off >>= 1)
        v += __shfl_down(v, off, 64);
    if ((tid & 63) == 0) s_red[tid >> 6] = v;
    __syncthreads();
    if (tid == 0)
        out[0] = (s_red[0] + s_red[1] + s_red[2] + s_red[3]) * scale;
}

extern "C" void kernel_launch(void* const* d_in, const int* in_sizes, int n_in,
                              void* d_out, int out_size, void* d_ws, size_t ws_size,
                              hipStream_t stream) {
    const float* y_true = (const float*)d_in[0];
    const float* y_pred = (const float*)d_in[1];
    float* out = (float*)d_out;
    float* hist = (float*)d_ws;
    float* slots = hist + NS * SLICE;      // 1.5 MB in, far past histograms
    int N = in_sizes[0];                   // 16384
    float scale = -0.5f / ((float)N * (float)N);

    bin_slices<<<NS, NTHR, 0, stream>>>(y_true, y_pred, hist, N);
    auc_main<<<NBLK, NTHR, 0, stream>>>(y_true, y_pred, hist, slots, N);
    auc_reduce<<<1, NTHR, 0, stream>>>(slots, out, scale);
}

// Round 3
// 71.455 us; speedup vs baseline: 1.0281x; 1.0281x over previous
//
#include <hip/hip_runtime.h>
#include <math.h>

// cost = -(1/N^2) sum_ij sigmoid(p_i p_j) relu(t_i - t_j)
//      = -(1/(2N^2)) sum_ij sigmoid(p_i p_j) |t_i - t_j|
// Separable O(N*PB): sigmoid(p_i p_j) ~= sum_b w_b(p_j) sigmoid(p_i q_b)
//   => S = sum_i sum_b sigmoid(p_i q_b) * M_b(t_i),
//      M_b(t) = sum_j w_b(p_j)|t - t_j|  (exact at TB+1 t-nodes via prefix
//      sums over t-binned (w, w*t) histograms; lerped between nodes).
//
// R3: evidence from R0(69.7, 1 node)/R1(70.3, 2 nodes)/R2(73.5, 3 nodes)
// with per-CU phase-A work varying 512x: total is dominated by fill(40us)
// + fixed per-iteration harness overhead; each extra graph node costs
// +0.6..3us; in-kernel tagged poll is ~free. So: ONE node, minimal body.
//  - 256 blocks (1/CU): halves R0's per-CU redundant phase-A scan.
//  - guard-column binning: one range check, both hat atomics uncond
//    inside; LDS row stride 8 (shift, no mul).
//  - R0's proven self-validating tagged-slot publish + block-0 poll
//    (works under any d_ws poison: uniform byte pattern => hi^lo==0).

#define TB 64                  // t-bins (TB+1 nodes); one wave64 scans it
#define PB 192                 // p-grid points over [PLO,PHI]
#define NBC 32                 // b-chunks
#define NBL 6                  // b per chunk = PB/NBC
#define NIC 8                  // i-chunks
#define NBLK (NBC * NIC)       // 256 blocks
#define NTHR 256
#define PLO (-5.0f)
#define PHI (5.0f)
#define TAG 0xA5A5A5A5u

__global__ __launch_bounds__(NTHR, 2) void auc_onepass(
    const float* __restrict__ t, const float* __restrict__ p,
    unsigned long long* __restrict__ slots, float* __restrict__ out,
    int N, float scale)
{
    __shared__ float sW[TB][NBL + 2];      // guard cols at 0 and NBL+1
    __shared__ float sP[TB][NBL + 2];
    __shared__ float sM[NBL][TB + 1];      // node tables
    __shared__ float s_red[4];

    const int bid = blockIdx.x;
    const int bc  = bid >> 3;              // / NIC
    const int ic  = bid & 7;               // % NIC
    const int B0  = bc * NBL;
    const int tid = threadIdx.x;

    // ---- zero private LDS histograms ----
    for (int idx = tid; idx < TB * (NBL + 2); idx += NTHR) {
        (&sW[0][0])[idx] = 0.0f;
        (&sP[0][0])[idx] = 0.0f;
    }
    __syncthreads();

    // ---- phase A: bin ALL N elements for this block's 6 b-columns ----
    const float pscale = (float)(PB - 1) / (PHI - PLO);
    const int itersA = N / (NTHR * 4);     // 16 for N=16384
    for (int it = 0; it < itersA; ++it) {
        const int j4 = (it * NTHR + tid) * 4;
        const float4 tv = *(const float4*)(t + j4);
        const float4 pv = *(const float4*)(p + j4);
        const float te[4] = {tv.x, tv.y, tv.z, tv.w};
        const float pe[4] = {pv.x, pv.y, pv.z, pv.w};
#pragma unroll
        for (int e = 0; e < 4; ++e) {
            float x = (pe[e] - PLO) * pscale;
            x = fminf(fmaxf(x, 0.0f), (float)(PB - 1) - 1e-4f);
            const int b0 = (int)x;
            const float f = x - (float)b0;
            const int tau = min(max((int)(te[e] * (float)TB), 0), TB - 1);
            const int c = b0 - B0 + 1;     // stored col; real col = c-1
            if ((unsigned)c <= (unsigned)NBL) {   // single guarded window
                const float w0 = 1.0f - f;
                atomicAdd(&sW[tau][c],     w0);
                atomicAdd(&sP[tau][c],     w0 * te[e]);
                atomicAdd(&sW[tau][c + 1], f);
                atomicAdd(&sP[tau][c + 1], f * te[e]);
            }
        }
    }
    __syncthreads();

    // ---- phase B: node tables via one-wave prefix scan ----
    // M_b(g) = g*(2A - Wtot) + (Ptot - 2B), A/B = exclusive prefixes below g
    {
        const int wv = tid >> 6, lane = tid & 63;
        for (int cc = wv; cc < NBL; cc += 4) {   // waves cover cols 0..5
            const float w = sW[lane][cc + 1];
            const float q = sP[lane][cc + 1];
            float wi = w, qi = q;          // inclusive scans
#pragma unroll
            for (int off = 1; off < 64; off <<= 1) {
                const float wn = __shfl_up(wi, off, 64);
                const float qn = __shfl_up(qi, off, 64);
                if (lane >= off) { wi += wn; qi += qn; }
            }
            const float Wtot = __shfl(wi, 63, 64);
            const float Ptot = __shfl(qi, 63, 64);
            const float A = wi - w;        // exclusive
            const float B = qi - q;
            const float g = (float)lane * (1.0f / (float)TB);
            sM[cc][lane] = g * (2.0f * A - Wtot) + (Ptot - 2.0f * B);
            if (lane == 63) sM[cc][TB] = Wtot - Ptot;   // node g = 1
        }
    }
    __syncthreads();

    // ---- phase C: partial S over (i-chunk) x (6 owned b's) ----
    const float h = (PHI - PLO) / (float)(PB - 1);
    const float q0 = PLO + (float)B0 * h;
    const int i0 = ic * (N / NIC);
    float acc = 0.0f;
    const int itersC = (N / NIC) / (NTHR * 4);   // 2 for N=16384
    for (int it = 0; it < itersC; ++it) {
        const int i4 = i0 + (it * NTHR + tid) * 4;
        const float4 tv = *(const float4*)(t + i4);
        const float4 pv = *(const float4*)(p + i4);
        const float te[4] = {tv.x, tv.y, tv.z, tv.w};
        const float pe[4] = {pv.x, pv.y, pv.z, pv.w};
#pragma unroll
        for (int e = 0; e < 4; ++e) {
            const float c = pe[e] * -1.44269504088896340736f;  // -log2(e)*p_i
            float x = te[e] * (float)TB;
            const int k = min((int)x, TB - 1);
            const float f = x - (float)k;
#pragma unroll
            for (int cc = 0; cc < NBL; ++cc) {
                const float m0 = sM[cc][k];
                const float m1 = sM[cc][k + 1];
                const float m  = fmaf(f, m1 - m0, m0);          // M_b(t_i)
                const float qb = q0 + (float)cc * h;
                const float ex = __builtin_amdgcn_exp2f(c * qb);
                const float sg = __builtin_amdgcn_rcpf(1.0f + ex);
                acc = fmaf(sg, m, acc);
            }
        }
    }

    // ---- block reduce ----
#pragma unroll
    for (int off = 32; off > 0; off >>= 1)
        acc += __shfl_down(acc, off, 64);
    if ((tid & 63) == 0) s_red[tid >> 6] = acc;
    __syncthreads();

    // ---- publish tagged partial (device scope) ----
    if (tid == 0) {
        const float part = s_red[0] + s_red[1] + s_red[2] + s_red[3];
        const unsigned int pb = __float_as_uint(part);
        const unsigned long long val =
            ((unsigned long long)pb << 32) | (unsigned long long)(pb ^ TAG);
        __hip_atomic_store(&slots[bid], val, __ATOMIC_RELEASE,
                           __HIP_MEMORY_SCOPE_AGENT);
    }

    // ---- block 0: poll all slots, deterministic sum, write out ----
    if (bid == 0) {
        float mine = 0.0f;
        for (int s = tid; s < NBLK; s += NTHR) {   // 1 slot/thread
            unsigned long long v;
            for (;;) {
                v = __hip_atomic_load(&slots[s], __ATOMIC_ACQUIRE,
                                      __HIP_MEMORY_SCOPE_AGENT);
                const unsigned int hi = (unsigned int)(v >> 32);
                const unsigned int lo = (unsigned int)v;
                if ((hi ^ lo) == TAG) break;
                __builtin_amdgcn_s_sleep(1);
            }
            mine += __uint_as_float((unsigned int)(v >> 32));
        }
#pragma unroll
        for (int off = 32; off > 0; off >>= 1)
            mine += __shfl_down(mine, off, 64);
        __syncthreads();                     // reuse s_red safely
        if ((tid & 63) == 0) s_red[tid >> 6] = mine;
        __syncthreads();
        if (tid == 0)
            out[0] = (s_red[0] + s_red[1] + s_red[2] + s_red[3]) * scale;
    }
}

extern "C" void kernel_launch(void* const* d_in, const int* in_sizes, int n_in,
                              void* d_out, int out_size, void* d_ws, size_t ws_size,
                              hipStream_t stream) {
    const float* y_true = (const float*)d_in[0];
    const float* y_pred = (const float*)d_in[1];
    float* out = (float*)d_out;
    unsigned long long* slots = (unsigned long long*)d_ws;
    int N = in_sizes[0];                     // 16384
    float scale = -0.5f / ((float)N * (float)N);

    auc_onepass<<<NBLK, NTHR, 0, stream>>>(y_true, y_pred, slots, out, N, scale);
}

// Round 4
// 68.957 us; speedup vs baseline: 1.0653x; 1.0362x over previous
//
#include <hip/hip_runtime.h>
#include <math.h>

// cost = -(1/N^2) sum_ij sigmoid(p_i p_j) relu(t_i - t_j)
//      = -(1/(2N^2)) sum_ij sigmoid(p_i p_j) |t_i - t_j|
// Separable O(N*PB): sigmoid(p_i p_j) ~= sum_b w_b(p_j) sigmoid(p_i q_b)
//   => S = sum_i sum_b sigmoid(p_i q_b) * M_b(t_i),
//      M_b(t) = sum_j w_b(p_j)|t - t_j|  (exact at TB+1 t-nodes via prefix
//      sums over t-binned (w, w*t) histograms; lerped between nodes).
//
// R4 = exact revert to R0 (best measured: 69.69us). Session evidence:
//  R0 69.69 (1 node, 512 blk = 2/CU)   <- this file
//  R1 70.33 (2 nodes, 256 blk)          -> node costs +0.6us
//  R2 73.46 (3 nodes, binning once)     -> work reduction irrelevant
//  R3 71.45 (1 node, 256 blk = 1/CU)    -> occupancy loss costs 1.8us
// Phase A is LATENCY-bound: 2 blocks/CU overlap their redundant scans;
// total = fill(40us @84% HBM, harness) + ~25us fixed overhead + ~5us us.
//
// SINGLE launch, NO grid sync (cg grid.sync costs ~50us on gfx950):
// each block owns (b-chunk of 3 grid points) x (i-chunk of N/8) and
// redundantly bins all N elements for just its 3 columns (LDS atomics,
// ~3% hit rate). Block partials are published as self-validating tagged
// 64-bit words (works whatever d_ws's initial contents are); block 0
// polls, sums in fixed order (deterministic), writes out. Only block 0
// waits -> deadlock-free under any dispatch order.

#define TB 64                  // t-bins (TB+1 nodes); one wave64 scans it
#define PB 192                 // p-grid points over [PLO,PHI]
#define NBC 64                 // b-chunks
#define NBL 3                  // b per chunk = PB/NBC
#define NIC 8                  // i-chunks
#define NBLK (NBC * NIC)       // 512 blocks
#define NTHR 256
#define PLO (-5.0f)
#define PHI (5.0f)
#define TAG 0xA5A5A5A5u

__global__ __launch_bounds__(NTHR, 2) void auc_onepass(
    const float* __restrict__ t, const float* __restrict__ p,
    unsigned long long* __restrict__ slots, float* __restrict__ out,
    int N, float scale)
{
    __shared__ float sW[TB][NBL + 1];      // +1 pad column
    __shared__ float sP[TB][NBL + 1];
    __shared__ float sM[NBL][TB + 1];      // node tables
    __shared__ float s_red[4];

    const int bid = blockIdx.x;
    const int bc  = bid >> 3;              // / NIC
    const int ic  = bid & 7;               // % NIC
    const int B0  = bc * NBL;
    const int tid = threadIdx.x;

    // ---- zero private LDS histograms ----
    for (int idx = tid; idx < TB * (NBL + 1); idx += NTHR) {
        (&sW[0][0])[idx] = 0.0f;
        (&sP[0][0])[idx] = 0.0f;
    }
    __syncthreads();

    // ---- phase A: bin ALL N elements for this block's 3 b-columns ----
    const float pscale = (float)(PB - 1) / (PHI - PLO);
    const int itersA = N / (NTHR * 4);     // 16 for N=16384
    for (int it = 0; it < itersA; ++it) {
        const int j4 = (it * NTHR + tid) * 4;
        const float4 tv = *(const float4*)(t + j4);
        const float4 pv = *(const float4*)(p + j4);
        const float te[4] = {tv.x, tv.y, tv.z, tv.w};
        const float pe[4] = {pv.x, pv.y, pv.z, pv.w};
#pragma unroll
        for (int e = 0; e < 4; ++e) {
            float x = (pe[e] - PLO) * pscale;
            x = fminf(fmaxf(x, 0.0f), (float)(PB - 1) - 1e-4f);
            const int b0 = (int)x;
            const float f = x - (float)b0;
            const int tau = min(max((int)(te[e] * (float)TB), 0), TB - 1);
            const int c0 = b0 - B0;
            if (c0 >= 0 && c0 < NBL) {
                atomicAdd(&sW[tau][c0], 1.0f - f);
                atomicAdd(&sP[tau][c0], (1.0f - f) * te[e]);
            }
            const int c1 = c0 + 1;
            if (c1 >= 0 && c1 < NBL) {
                atomicAdd(&sW[tau][c1], f);
                atomicAdd(&sP[tau][c1], f * te[e]);
            }
        }
    }
    __syncthreads();

    // ---- phase B: node tables via one-wave prefix scan; wave w -> col w ----
    // M_b(g) = g*(2A - Wtot) + (Ptot - 2B), A/B = exclusive prefixes below g
    {
        const int wv = tid >> 6, lane = tid & 63;
        if (wv < NBL) {
            const float w = sW[lane][wv];
            const float q = sP[lane][wv];
            float wi = w, qi = q;          // inclusive scans
#pragma unroll
            for (int off = 1; off < 64; off <<= 1) {
                const float wn = __shfl_up(wi, off, 64);
                const float qn = __shfl_up(qi, off, 64);
                if (lane >= off) { wi += wn; qi += qn; }
            }
            const float Wtot = __shfl(wi, 63, 64);
            const float Ptot = __shfl(qi, 63, 64);
            const float A = wi - w;        // exclusive
            const float B = qi - q;
            const float g = (float)lane * (1.0f / (float)TB);
            sM[wv][lane] = g * (2.0f * A - Wtot) + (Ptot - 2.0f * B);
            if (lane == 63) sM[wv][TB] = Wtot - Ptot;   // node g = 1
        }
    }
    __syncthreads();

    // ---- phase C: partial S over (i-chunk) x (3 owned b's) ----
    const float h = (PHI - PLO) / (float)(PB - 1);
    const float q0 = PLO + (float)B0 * h;
    const int i0 = ic * (N / NIC);
    float acc = 0.0f;
    const int itersC = (N / NIC) / (NTHR * 4);   // 2 for N=16384
    for (int it = 0; it < itersC; ++it) {
        const int i4 = i0 + (it * NTHR + tid) * 4;
        const float4 tv = *(const float4*)(t + i4);
        const float4 pv = *(const float4*)(p + i4);
        const float te[4] = {tv.x, tv.y, tv.z, tv.w};
        const float pe[4] = {pv.x, pv.y, pv.z, pv.w};
#pragma unroll
        for (int e = 0; e < 4; ++e) {
            const float c = pe[e] * -1.44269504088896340736f;  // -log2(e)*p_i
            float x = te[e] * (float)TB;
            const int k = min((int)x, TB - 1);
            const float f = x - (float)k;
#pragma unroll
            for (int cc = 0; cc < NBL; ++cc) {
                const float m0 = sM[cc][k];
                const float m1 = sM[cc][k + 1];
                const float m  = fmaf(f, m1 - m0, m0);          // M_b(t_i)
                const float qb = q0 + (float)cc * h;
                const float ex = __builtin_amdgcn_exp2f(c * qb);
                const float sg = __builtin_amdgcn_rcpf(1.0f + ex);
                acc = fmaf(sg, m, acc);
            }
        }
    }

    // ---- block reduce ----
#pragma unroll
    for (int off = 32; off > 0; off >>= 1)
        acc += __shfl_down(acc, off, 64);
    if ((tid & 63) == 0) s_red[tid >> 6] = acc;
    __syncthreads();

    // ---- publish tagged partial (device scope) ----
    if (tid == 0) {
        const float part = s_red[0] + s_red[1] + s_red[2] + s_red[3];
        const unsigned int pb = __float_as_uint(part);
        const unsigned long long val =
            ((unsigned long long)pb << 32) | (unsigned long long)(pb ^ TAG);
        __hip_atomic_store(&slots[bid], val, __ATOMIC_RELEASE,
                           __HIP_MEMORY_SCOPE_AGENT);
    }

    // ---- block 0: poll all slots, deterministic sum, write out ----
    if (bid == 0) {
        float mine = 0.0f;
        for (int s = tid; s < NBLK; s += NTHR) {
            unsigned long long v;
            for (;;) {
                v = __hip_atomic_load(&slots[s], __ATOMIC_ACQUIRE,
                                      __HIP_MEMORY_SCOPE_AGENT);
                const unsigned int hi = (unsigned int)(v >> 32);
                const unsigned int lo = (unsigned int)v;
                if ((hi ^ lo) == TAG) break;
                __builtin_amdgcn_s_sleep(1);
            }
            mine += __uint_as_float((unsigned int)(v >> 32));
        }
#pragma unroll
        for (int off = 32; off > 0; off >>= 1)
            mine += __shfl_down(mine, off, 64);
        __syncthreads();                     // reuse s_red safely
        if ((tid & 63) == 0) s_red[tid >> 6] = mine;
        __syncthreads();
        if (tid == 0)
            out[0] = (s_red[0] + s_red[1] + s_red[2] + s_red[3]) * scale;
    }
}

extern "C" void kernel_launch(void* const* d_in, const int* in_sizes, int n_in,
                              void* d_out, int out_size, void* d_ws, size_t ws_size,
                              hipStream_t stream) {
    const float* y_true = (const float*)d_in[0];
    const float* y_pred = (const float*)d_in[1];
    float* out = (float*)d_out;
    unsigned long long* slots = (unsigned long long*)d_ws;
    int N = in_sizes[0];                     // 16384
    float scale = -0.5f / ((float)N * (float)N);

    auc_onepass<<<NBLK, NTHR, 0, stream>>>(y_true, y_pred, slots, out, N, scale);
}